// Round 1
// baseline (4162.146 us; speedup 1.0000x reference)
//
#include <hip/hip_runtime.h>
#include <cstddef>

// ---------------------------------------------------------------------------
// Encoder: two cross-attentions + segment means, algebraically reduced.
//   out[b] = concat( mean_q(attn1) @ Wo^T + bo , mean_q(attn2) @ Wo^T + bo )
// where mean-over-queries of P@V collapses to softmax column-sums.
// ---------------------------------------------------------------------------

namespace {
constexpr int B_   = 3;
constexpr int S_   = 4096;
constexpr int H_   = 1024;
constexpr int NH_  = 32;
constexpr int DK_  = 32;
constexpr int SEG1 = 1;     // queries of mha0 / keys of mha1 start row
constexpr int SEG2 = 2049;  // keys of mha0 / queries of mha1 start row
constexpr int NQ1  = 2048;  // mha0: #queries (rows 1..2048)
constexpr int NK1  = 2047;  // mha0: #keys    (rows 2049..4095)
constexpr int NQ2  = 2047;  // mha1: #queries
constexpr int NK2  = 2048;  // mha1: #keys
constexpr float SCALE = 0.17677669529663687f;  // 1/sqrt(32)

// workspace layout (float units)
constexpr size_t oQ  = 0;
constexpr size_t oK  = oQ + (size_t)B_ * S_ * H_;            // 12582912
constexpr size_t oMZ = oK + (size_t)B_ * S_ * H_;            // 25165824, size 6*2048*2
constexpr size_t oCS = oMZ + (size_t)6 * 2048 * 2;           // size 6*32*2048
constexpr size_t oU  = oCS + (size_t)6 * NH_ * 2048;         // size 6*32*1024
constexpr size_t oM  = oU + (size_t)6 * NH_ * H_;            // size 6*1024
}

// ---------------------------------------------------------------------------
// Projection GEMM: C[m][n] = sum_k X[m][k] * W[n][k] + bias[n]
// M = B*S = 12288 rows (rows 0 per batch are unused but harmless), N=K=1024.
// 128x128 tile, BK=8, 256 threads, 8x8 per thread.
// ---------------------------------------------------------------------------
__global__ __launch_bounds__(256) void proj_gemm(
    const float* __restrict__ X, const float* __restrict__ W,
    const float* __restrict__ bias, float* __restrict__ C)
{
    __shared__ float As[8][132];
    __shared__ float Bs[8][132];
    const int tid = threadIdx.x;
    const int m0 = blockIdx.x * 128;
    const int n0 = blockIdx.y * 128;
    const int tx = tid & 15, ty = tid >> 4;
    const int lr = tid >> 1;
    const int lc = (tid & 1) * 4;

    float acc[8][8] = {};

    for (int k0 = 0; k0 < H_; k0 += 8) {
        float4 av = *(const float4*)&X[(size_t)(m0 + lr) * H_ + k0 + lc];
        float4 bv = *(const float4*)&W[(size_t)(n0 + lr) * H_ + k0 + lc];
        __syncthreads();   // protect previous iteration's reads
        As[lc + 0][lr] = av.x; As[lc + 1][lr] = av.y;
        As[lc + 2][lr] = av.z; As[lc + 3][lr] = av.w;
        Bs[lc + 0][lr] = bv.x; Bs[lc + 1][lr] = bv.y;
        Bs[lc + 2][lr] = bv.z; Bs[lc + 3][lr] = bv.w;
        __syncthreads();
#pragma unroll
        for (int kk = 0; kk < 8; ++kk) {
            float a[8], b[8];
            *(float4*)&a[0] = *(const float4*)&As[kk][ty * 8];
            *(float4*)&a[4] = *(const float4*)&As[kk][ty * 8 + 4];
            *(float4*)&b[0] = *(const float4*)&Bs[kk][tx * 8];
            *(float4*)&b[4] = *(const float4*)&Bs[kk][tx * 8 + 4];
#pragma unroll
            for (int i = 0; i < 8; ++i)
#pragma unroll
                for (int j = 0; j < 8; ++j)
                    acc[i][j] += a[i] * b[j];
        }
    }

#pragma unroll
    for (int i = 0; i < 8; ++i) {
        const int m = m0 + ty * 8 + i;
#pragma unroll
        for (int j = 0; j < 8; j += 4) {
            float4 o;
            o.x = acc[i][j + 0] + bias[n0 + tx * 8 + j + 0];
            o.y = acc[i][j + 1] + bias[n0 + tx * 8 + j + 1];
            o.z = acc[i][j + 2] + bias[n0 + tx * 8 + j + 2];
            o.w = acc[i][j + 3] + bias[n0 + tx * 8 + j + 3];
            *(float4*)&C[(size_t)m * H_ + n0 + tx * 8 + j] = o;
        }
    }
}

// ---------------------------------------------------------------------------
// Pass A: per-query softmax stats (running max M and denom Z).
// grid: (qtile=32, head=32, bm=6); block 256. Each block: 64 queries x all keys.
// ---------------------------------------------------------------------------
__global__ __launch_bounds__(256) void attn_stats(
    const float* __restrict__ Qb, const float* __restrict__ Kb,
    float* __restrict__ MZ)
{
    __shared__ float Qs[64][36];
    __shared__ float Ks[64][36];
    const int tid = threadIdx.x;
    const int bm = blockIdx.z;
    const int b = bm >> 1, mha = bm & 1;
    const int h = blockIdx.y;
    const int q0 = blockIdx.x * 64;
    const int qbase = mha ? SEG2 : SEG1;
    const int kbase = mha ? SEG1 : SEG2;
    const int nq = mha ? NQ2 : NQ1;
    const int nk = mha ? NK2 : NK1;
    const size_t rowbase = (size_t)b * S_;
    const int hoff = h * DK_;

    {   // load Q tile (clamped rows; clamped rows' results are discarded)
        const int r = tid >> 2;
        const int dd = (tid & 3) * 8;
        const int qr = min(q0 + r, nq - 1);
        const float* src = &Qb[(rowbase + qbase + qr) * H_ + hoff + dd];
        *(float4*)&Qs[r][dd]     = *(const float4*)&src[0];
        *(float4*)&Qs[r][dd + 4] = *(const float4*)&src[4];
    }

    const int tx = tid & 15, ty = tid >> 4;
    float mrow[4], zrow[4];
#pragma unroll
    for (int i = 0; i < 4; ++i) { mrow[i] = -1e30f; zrow[i] = 0.f; }

    const int nkt = (nk + 63) >> 6;
    for (int kt = 0; kt < nkt; ++kt) {
        const int k0 = kt * 64;
        __syncthreads();
        {
            const int r = tid >> 2;
            const int dd = (tid & 3) * 8;
            const int kr = min(k0 + r, nk - 1);
            const float* src = &Kb[(rowbase + kbase + kr) * H_ + hoff + dd];
            *(float4*)&Ks[r][dd]     = *(const float4*)&src[0];
            *(float4*)&Ks[r][dd + 4] = *(const float4*)&src[4];
        }
        __syncthreads();

        float s[4][4] = {};
#pragma unroll
        for (int d0 = 0; d0 < DK_; d0 += 4) {
            float4 qv[4], kv[4];
#pragma unroll
            for (int i = 0; i < 4; ++i) qv[i] = *(const float4*)&Qs[ty * 4 + i][d0];
#pragma unroll
            for (int j = 0; j < 4; ++j) kv[j] = *(const float4*)&Ks[tx + 16 * j][d0];
#pragma unroll
            for (int i = 0; i < 4; ++i)
#pragma unroll
                for (int j = 0; j < 4; ++j)
                    s[i][j] += qv[i].x * kv[j].x + qv[i].y * kv[j].y +
                               qv[i].z * kv[j].z + qv[i].w * kv[j].w;
        }
#pragma unroll
        for (int i = 0; i < 4; ++i) {
            const float s0 = (k0 + tx      < nk) ? s[i][0] * SCALE : -1e30f;
            const float s1 = (k0 + tx + 16 < nk) ? s[i][1] * SCALE : -1e30f;
            const float s2 = (k0 + tx + 32 < nk) ? s[i][2] * SCALE : -1e30f;
            const float s3 = (k0 + tx + 48 < nk) ? s[i][3] * SCALE : -1e30f;
            const float tm = fmaxf(fmaxf(s0, s1), fmaxf(s2, s3));
            const float nm = fmaxf(mrow[i], tm);
            const float zadd = __expf(s0 - nm) + __expf(s1 - nm) +
                               __expf(s2 - nm) + __expf(s3 - nm);
            zrow[i] = zrow[i] * __expf(mrow[i] - nm) + zadd;
            mrow[i] = nm;
        }
    }

    // merge (m,z) across the 16 tx lanes (same wave)
#pragma unroll
    for (int i = 0; i < 4; ++i) {
        float m = mrow[i], z = zrow[i];
#pragma unroll
        for (int off = 8; off >= 1; off >>= 1) {
            const float mo = __shfl_xor(m, off, 64);
            const float zo = __shfl_xor(z, off, 64);
            const float nm = fmaxf(m, mo);
            z = z * __expf(m - nm) + zo * __expf(mo - nm);
            m = nm;
        }
        if (tx == 0) {
            const int q = q0 + ty * 4 + i;
            if (q < nq) {
                const size_t idx = ((size_t)bm * 2048 + q) * 2;
                MZ[idx] = m; MZ[idx + 1] = z;
            }
        }
    }
}

// ---------------------------------------------------------------------------
// Pass B: recompute scores, p = exp(s-M)/Z, accumulate column sums.
// ---------------------------------------------------------------------------
__global__ __launch_bounds__(256) void attn_colsum(
    const float* __restrict__ Qb, const float* __restrict__ Kb,
    const float* __restrict__ MZ, float* __restrict__ CS)
{
    __shared__ float Qs[64][36];
    __shared__ float Ks[64][36];
    __shared__ float csum[2048];
    const int tid = threadIdx.x;
    const int bm = blockIdx.z;
    const int b = bm >> 1, mha = bm & 1;
    const int h = blockIdx.y;
    const int q0 = blockIdx.x * 64;
    const int qbase = mha ? SEG2 : SEG1;
    const int kbase = mha ? SEG1 : SEG2;
    const int nq = mha ? NQ2 : NQ1;
    const int nk = mha ? NK2 : NK1;
    const size_t rowbase = (size_t)b * S_;
    const int hoff = h * DK_;

    for (int idx = tid; idx < 2048; idx += 256) csum[idx] = 0.f;

    {
        const int r = tid >> 2;
        const int dd = (tid & 3) * 8;
        const int qr = min(q0 + r, nq - 1);
        const float* src = &Qb[(rowbase + qbase + qr) * H_ + hoff + dd];
        *(float4*)&Qs[r][dd]     = *(const float4*)&src[0];
        *(float4*)&Qs[r][dd + 4] = *(const float4*)&src[4];
    }

    const int tx = tid & 15, ty = tid >> 4;
    float Mq[4], iZ[4];
#pragma unroll
    for (int i = 0; i < 4; ++i) {
        const int q = q0 + ty * 4 + i;
        if (q < nq) {
            const size_t idx = ((size_t)bm * 2048 + q) * 2;
            Mq[i] = MZ[idx];
            iZ[i] = 1.f / MZ[idx + 1];
        } else { Mq[i] = 0.f; iZ[i] = 0.f; }
    }

    const int nkt = (nk + 63) >> 6;
    for (int kt = 0; kt < nkt; ++kt) {
        const int k0 = kt * 64;
        __syncthreads();
        {
            const int r = tid >> 2;
            const int dd = (tid & 3) * 8;
            const int kr = min(k0 + r, nk - 1);
            const float* src = &Kb[(rowbase + kbase + kr) * H_ + hoff + dd];
            *(float4*)&Ks[r][dd]     = *(const float4*)&src[0];
            *(float4*)&Ks[r][dd + 4] = *(const float4*)&src[4];
        }
        __syncthreads();

        float s[4][4] = {};
#pragma unroll
        for (int d0 = 0; d0 < DK_; d0 += 4) {
            float4 qv[4], kv[4];
#pragma unroll
            for (int i = 0; i < 4; ++i) qv[i] = *(const float4*)&Qs[ty * 4 + i][d0];
#pragma unroll
            for (int j = 0; j < 4; ++j) kv[j] = *(const float4*)&Ks[tx + 16 * j][d0];
#pragma unroll
            for (int i = 0; i < 4; ++i)
#pragma unroll
                for (int j = 0; j < 4; ++j)
                    s[i][j] += qv[i].x * kv[j].x + qv[i].y * kv[j].y +
                               qv[i].z * kv[j].z + qv[i].w * kv[j].w;
        }
        float psum[4] = {0.f, 0.f, 0.f, 0.f};
#pragma unroll
        for (int j = 0; j < 4; ++j) {
            const bool vk = (k0 + tx + 16 * j) < nk;
#pragma unroll
            for (int i = 0; i < 4; ++i) {
                float p = __expf(s[i][j] * SCALE - Mq[i]) * iZ[i];
                psum[j] += vk ? p : 0.f;
            }
        }
#pragma unroll
        for (int j = 0; j < 4; ++j)
            atomicAdd(&csum[k0 + tx + 16 * j], psum[j]);
    }

    __syncthreads();
    for (int idx = tid; idx < nk; idx += 256)
        atomicAdd(&CS[((size_t)bm * NH_ + h) * 2048 + idx], csum[idx]);
}

// ---------------------------------------------------------------------------
// Pass C: u[bm][h][c] = sum_k CS[bm][h][k] * X[kbase+k][c]
// grid: (ktile=16, headgroup=4, bm=6); block 256 (one col-quad per thread).
// ---------------------------------------------------------------------------
__global__ __launch_bounds__(256) void colsum_x(
    const float* __restrict__ X, const float* __restrict__ CS,
    float* __restrict__ U)
{
    __shared__ float sl[8][128];
    const int tid = threadIdx.x;
    const int bm = blockIdx.z;
    const int b = bm >> 1, mha = bm & 1;
    const int kbase = mha ? SEG1 : SEG2;
    const int nk = mha ? NK2 : NK1;
    const int kt = blockIdx.x * 128;
    const int hg = blockIdx.y * 8;

    for (int idx = tid; idx < 8 * 128; idx += 256) {
        const int hh = idx >> 7, kk = idx & 127;
        const int k = kt + kk;
        sl[hh][kk] = (k < nk) ? CS[((size_t)bm * NH_ + hg + hh) * 2048 + k] : 0.f;
    }
    __syncthreads();

    float acc[8][4] = {};
    const int c4 = tid * 4;
    for (int kk = 0; kk < 128; ++kk) {
        const int k = kt + kk;
        if (k >= nk) break;  // uniform across block
        const float4 xv = *(const float4*)&X[((size_t)b * S_ + kbase + k) * H_ + c4];
#pragma unroll
        for (int hh = 0; hh < 8; ++hh) {
            const float sv = sl[hh][kk];
            acc[hh][0] += sv * xv.x; acc[hh][1] += sv * xv.y;
            acc[hh][2] += sv * xv.z; acc[hh][3] += sv * xv.w;
        }
    }
#pragma unroll
    for (int hh = 0; hh < 8; ++hh)
#pragma unroll
        for (int c = 0; c < 4; ++c)
            atomicAdd(&U[((size_t)bm * NH_ + hg + hh) * H_ + c4 + c], acc[hh][c]);
}

// ---------------------------------------------------------------------------
// Pass D: m[bm][o] = (1/nq) * dot(u[bm][o/32][:], Wv[o][:]) + bv[o]
// ---------------------------------------------------------------------------
__global__ __launch_bounds__(256) void compute_m(
    const float* __restrict__ U, const float* __restrict__ Wv,
    const float* __restrict__ bv, float* __restrict__ Mvec)
{
    const int bm = blockIdx.y;
    const int mha = bm & 1;
    const float invnq = 1.f / (float)(mha ? NQ2 : NQ1);
    const int o = blockIdx.x * 256 + threadIdx.x;
    const int hh = o >> 5;
    const float* u = &U[((size_t)bm * NH_ + hh) * H_];
    const float* w = &Wv[(size_t)o * H_];
    float acc = 0.f;
    for (int in = 0; in < H_; in += 4) {
        const float4 uv = *(const float4*)&u[in];
        const float4 wv = *(const float4*)&w[in];
        acc += uv.x * wv.x + uv.y * wv.y + uv.z * wv.z + uv.w * wv.w;
    }
    Mvec[(size_t)bm * H_ + o] = acc * invnq + bv[o];
}

// ---------------------------------------------------------------------------
// Pass E: out[b][mha*1024 + o] = dot(m[bm][:], Wo[o][:]) + bo[o]
// ---------------------------------------------------------------------------
__global__ __launch_bounds__(256) void final_out(
    const float* __restrict__ Mvec, const float* __restrict__ Wo,
    const float* __restrict__ bo, float* __restrict__ out)
{
    const int bm = blockIdx.y;
    const int b = bm >> 1, mha = bm & 1;
    const int o = blockIdx.x * 256 + threadIdx.x;
    const float* mv = &Mvec[(size_t)bm * H_];
    const float* w = &Wo[(size_t)o * H_];
    float acc = 0.f;
    for (int in = 0; in < H_; in += 4) {
        const float4 mvv = *(const float4*)&mv[in];
        const float4 wv = *(const float4*)&w[in];
        acc += mvv.x * wv.x + mvv.y * wv.y + mvv.z * wv.z + mvv.w * wv.w;
    }
    out[(size_t)b * 2048 + mha * 1024 + o] = acc + bo[o];
}

// ---------------------------------------------------------------------------
extern "C" void kernel_launch(void* const* d_in, const int* in_sizes, int n_in,
                              void* d_out, int out_size, void* d_ws, size_t ws_size,
                              hipStream_t stream)
{
    const float* hidden = (const float*)d_in[0];
    const float* Wq = (const float*)d_in[7];
    const float* bq = (const float*)d_in[8];
    const float* Wk = (const float*)d_in[9];
    const float* bk = (const float*)d_in[10];
    const float* Wv = (const float*)d_in[11];
    const float* bv = (const float*)d_in[12];
    const float* Wo = (const float*)d_in[13];
    const float* bo = (const float*)d_in[14];
    float* out = (float*)d_out;
    float* ws = (float*)d_ws;

    float* Qb = ws + oQ;
    float* Kb = ws + oK;
    float* MZ = ws + oMZ;
    float* CS = ws + oCS;
    float* U  = ws + oU;
    float* Mv = ws + oM;

    // zero the atomic accumulators (CS and U are contiguous)
    hipMemsetAsync(CS, 0, (size_t)(6 * NH_ * 2048 + 6 * NH_ * H_) * sizeof(float), stream);

    const dim3 blk(256);
    proj_gemm<<<dim3(96, 8), blk, 0, stream>>>(hidden, Wq, bq, Qb);
    proj_gemm<<<dim3(96, 8), blk, 0, stream>>>(hidden, Wk, bk, Kb);
    attn_stats<<<dim3(32, 32, 6), blk, 0, stream>>>(Qb, Kb, MZ);
    attn_colsum<<<dim3(32, 32, 6), blk, 0, stream>>>(Qb, Kb, MZ, CS);
    colsum_x<<<dim3(16, 4, 6), blk, 0, stream>>>(hidden, CS, U);
    compute_m<<<dim3(4, 6), blk, 0, stream>>>(U, Wv, bv, Mv);
    final_out<<<dim3(4, 6), blk, 0, stream>>>(Mv, Wo, bo, out);
}

// Round 2
// 1012.570 us; speedup vs baseline: 4.1105x; 4.1105x over previous
//
#include <hip/hip_runtime.h>
#include <cstddef>

typedef __attribute__((ext_vector_type(8))) short bf16x8;
typedef __attribute__((ext_vector_type(4))) float f32x4;
typedef __attribute__((ext_vector_type(4))) unsigned short u16x4;
typedef __attribute__((ext_vector_type(8))) unsigned short u16x8;

namespace {
constexpr int B_ = 3, S_ = 4096, H_ = 1024, NH_ = 32;
constexpr int SEG1 = 1, SEG2 = 2049;
constexpr int NQ1 = 2048, NK1 = 2047, NQ2 = 2047, NK2 = 2048;
constexpr float SCALE = 0.17677669529663687f;  // 1/sqrt(32), folded into Wq/bq

// workspace byte offsets (all 16B aligned)
constexpr size_t oXb = 0;                                   // 12288*1024 bf16
constexpr size_t oWb = oXb + (size_t)12288 * 1024 * 2;      // 2048*1024 bf16
constexpr size_t oBB = oWb + (size_t)2048 * 1024 * 2;       // 2048 f32
constexpr size_t oQK = oBB + (size_t)2048 * 4;              // 12304*2048 bf16 (16 pad rows)
constexpr size_t oIZ = oQK + (size_t)12304 * 2048 * 2;      // 6*2048 f32
constexpr size_t oCS = oIZ + (size_t)6 * 2048 * 4;          // 6*32*2048 f32
constexpr size_t oU  = oCS + (size_t)6 * 32 * 2048 * 4;     // 6*32*1024 f32
constexpr size_t oMv = oU  + (size_t)6 * 32 * 1024 * 4;     // 6*1024 f32
}

__device__ __forceinline__ unsigned short f2bf(float f) {
    unsigned u = __float_as_uint(f);
    u += 0x7FFF + ((u >> 16) & 1);   // RTNE
    return (unsigned short)(u >> 16);
}

// ---------------------------------------------------------------------------
// fp32 -> bf16 conversion of hidden states
// ---------------------------------------------------------------------------
__global__ __launch_bounds__(256) void conv_x(const float* __restrict__ X,
                                              unsigned short* __restrict__ Xb)
{
    const size_t i4 = (size_t)blockIdx.x * 256 + threadIdx.x;   // 12288*256 groups of 4
    const float4 v = *(const float4*)&X[i4 * 4];
    u16x4 o;
    o[0] = f2bf(v.x); o[1] = f2bf(v.y); o[2] = f2bf(v.z); o[3] = f2bf(v.w);
    *(u16x4*)&Xb[i4 * 4] = o;
}

// pack [SCALE*Wq ; Wk] -> bf16, [SCALE*bq ; bk] -> f32
__global__ __launch_bounds__(256) void conv_w(const float* __restrict__ Wq,
                                              const float* __restrict__ bq,
                                              const float* __restrict__ Wk,
                                              const float* __restrict__ bk,
                                              unsigned short* __restrict__ Wb,
                                              float* __restrict__ bb)
{
    const int i4 = blockIdx.x * 256 + threadIdx.x;  // 0..524287
    const int base = i4 * 4;
    const bool isQ = base < (1 << 20);
    const float sc = isQ ? SCALE : 1.f;
    const float* src = isQ ? &Wq[base] : &Wk[base - (1 << 20)];
    const float4 v = *(const float4*)src;
    u16x4 o;
    o[0] = f2bf(v.x * sc); o[1] = f2bf(v.y * sc);
    o[2] = f2bf(v.z * sc); o[3] = f2bf(v.w * sc);
    *(u16x4*)&Wb[base] = o;
    if (base < 2048) {
#pragma unroll
        for (int c = 0; c < 4; ++c) {
            const int j = base + c;
            bb[j] = (j < 1024) ? SCALE * bq[j] : bk[j - 1024];
        }
    }
}

// ---------------------------------------------------------------------------
// Fused Q|K projection: QK[m][0..1023] = (X Wq^T + bq)*SCALE, [1024..2047] = X Wk^T + bk
// bf16 MFMA, 128x128 tile, BK=32, 4 waves (2x2 of 64x64). LDS pitch 80B (conflict-free).
// ---------------------------------------------------------------------------
__global__ __launch_bounds__(256) void proj_mfma(const unsigned short* __restrict__ Xb,
                                                 const unsigned short* __restrict__ Wb,
                                                 const float* __restrict__ bb,
                                                 unsigned short* __restrict__ QK)
{
    __shared__ unsigned short lds[2 * 128 * 40];   // A then B, pitch 40 ushorts = 80B
    const int tid = threadIdx.x;
    const int lane = tid & 63, w = tid >> 6;
    const int m0 = blockIdx.x * 128, n0 = blockIdx.y * 128;
    const int wr = (w >> 1) * 64, wc = (w & 1) * 64;
    const int Gr = tid >> 2, Gg = tid & 3;         // staging row / 16B-granule

    const unsigned short* gA = &Xb[(size_t)(m0 + Gr) * 1024 + Gg * 8];
    const unsigned short* gB = &Wb[(size_t)(n0 + Gr) * 1024 + Gg * 8];
    unsigned short* sA = &lds[Gr * 40 + Gg * 8];
    unsigned short* sB = &lds[128 * 40 + Gr * 40 + Gg * 8];
    const unsigned short* fA = &lds[(wr + (lane & 15)) * 40 + (lane >> 4) * 8];
    const unsigned short* fB = &lds[128 * 40 + (wc + (lane & 15)) * 40 + (lane >> 4) * 8];

    f32x4 acc[4][4] = {};
    u16x8 rA0 = *(const u16x8*)(gA);
    u16x8 rA1 = *(const u16x8*)(gA + 64 * 1024);
    u16x8 rB0 = *(const u16x8*)(gB);
    u16x8 rB1 = *(const u16x8*)(gB + 64 * 1024);

    for (int k0 = 0; k0 < 1024; k0 += 32) {
        __syncthreads();
        *(u16x8*)(sA) = rA0; *(u16x8*)(sA + 64 * 40) = rA1;
        *(u16x8*)(sB) = rB0; *(u16x8*)(sB + 64 * 40) = rB1;
        __syncthreads();
        if (k0 + 32 < 1024) {
            rA0 = *(const u16x8*)(gA + k0 + 32);
            rA1 = *(const u16x8*)(gA + 64 * 1024 + k0 + 32);
            rB0 = *(const u16x8*)(gB + k0 + 32);
            rB1 = *(const u16x8*)(gB + 64 * 1024 + k0 + 32);
        }
        bf16x8 a[4], b[4];
#pragma unroll
        for (int i = 0; i < 4; ++i) a[i] = *(const bf16x8*)(fA + i * 16 * 40);
#pragma unroll
        for (int j = 0; j < 4; ++j) b[j] = *(const bf16x8*)(fB + j * 16 * 40);
#pragma unroll
        for (int i = 0; i < 4; ++i)
#pragma unroll
            for (int j = 0; j < 4; ++j)
                acc[i][j] = __builtin_amdgcn_mfma_f32_16x16x32_bf16(a[i], b[j], acc[i][j], 0, 0, 0);
    }

#pragma unroll
    for (int j = 0; j < 4; ++j) {
        const int col = n0 + wc + 16 * j + (lane & 15);
        const float bias = bb[col];
#pragma unroll
        for (int i = 0; i < 4; ++i) {
            const int rowb = m0 + wr + 16 * i + (lane >> 4) * 4;
#pragma unroll
            for (int r = 0; r < 4; ++r)
                QK[(size_t)(rowb + r) * 2048 + col] = f2bf(acc[i][j][r] + bias);
        }
    }
}

// ---------------------------------------------------------------------------
// Pass 1: iZ[bm][q] = 1 / sum_k exp(s[q][k])   (no max-sub; |s|<~4 is exp-safe)
// grid (32 qtiles, 32 heads, 6 bm); wave w owns 16 q rows. 64 k per iter.
// ---------------------------------------------------------------------------
__global__ __launch_bounds__(256) void zpass(const unsigned short* __restrict__ QK,
                                             float* __restrict__ iZ)
{
    const int tid = threadIdx.x, lane = tid & 63, w = tid >> 6;
    const int bm = blockIdx.z, b = bm >> 1, mha = bm & 1;
    const int h = blockIdx.y;
    const int q0 = blockIdx.x * 64 + w * 16;
    const int qrow = b * S_ + (mha ? SEG2 : SEG1);
    const int krow = b * S_ + (mha ? SEG1 : SEG2);
    const int nk = mha ? NK2 : NK1, nq = mha ? NQ2 : NQ1;
    const int dsl = (lane >> 4) * 8;
    const f32x4 zero = {0.f, 0.f, 0.f, 0.f};

    const bf16x8 a = *(const bf16x8*)&QK[(size_t)(qrow + q0 + (lane & 15)) * 2048 + h * 32 + dsl];
    const unsigned short* Kp = &QK[(size_t)(krow + (lane & 15)) * 2048 + 1024 + h * 32 + dsl];

    float z[4] = {0.f, 0.f, 0.f, 0.f};
    for (int kt = 0; kt < 31; ++kt) {
        const unsigned short* p = Kp + (size_t)kt * 64 * 2048;
#pragma unroll
        for (int j = 0; j < 4; ++j) {
            const bf16x8 bj = *(const bf16x8*)(p + (size_t)j * 16 * 2048);
            const f32x4 d = __builtin_amdgcn_mfma_f32_16x16x32_bf16(a, bj, zero, 0, 0, 0);
#pragma unroll
            for (int r = 0; r < 4; ++r) z[r] += __expf(d[r]);
        }
    }
    {   // tail tile (k 1984..2047) with column mask
        const unsigned short* p = Kp + (size_t)31 * 64 * 2048;
        const int c0 = 1984 + (lane & 15);
#pragma unroll
        for (int j = 0; j < 4; ++j) {
            const bf16x8 bj = *(const bf16x8*)(p + (size_t)j * 16 * 2048);
            const f32x4 d = __builtin_amdgcn_mfma_f32_16x16x32_bf16(a, bj, zero, 0, 0, 0);
            const float m = (c0 + 16 * j < nk) ? 1.f : 0.f;
#pragma unroll
            for (int r = 0; r < 4; ++r) z[r] += m * __expf(d[r]);
        }
    }
    // sum over the 16 lanes of each row-group
#pragma unroll
    for (int r = 0; r < 4; ++r) {
        float v = z[r];
        v += __shfl_xor(v, 1, 64);
        v += __shfl_xor(v, 2, 64);
        v += __shfl_xor(v, 4, 64);
        v += __shfl_xor(v, 8, 64);
        z[r] = v;
    }
    if ((lane & 15) == 0) {
        const int qb = q0 + (lane >> 4) * 4;
        f32x4 o;
#pragma unroll
        for (int r = 0; r < 4; ++r)
            o[r] = (qb + r < nq) ? 1.f / z[r] : 0.f;   // 0 masks padded q rows in pass 2
        *(f32x4*)&iZ[(size_t)bm * 2048 + qb] = o;
    }
}

// ---------------------------------------------------------------------------
// Pass 2: CS[bm][h][k] = sum_q exp(s[q][k]) * iZ[q]. Block owns 64 cols; no atomics.
// ---------------------------------------------------------------------------
__global__ __launch_bounds__(256) void colsum(const unsigned short* __restrict__ QK,
                                              const float* __restrict__ iZ,
                                              float* __restrict__ CS)
{
    const int tid = threadIdx.x, lane = tid & 63, w = tid >> 6;
    const int bm = blockIdx.z, b = bm >> 1, mha = bm & 1;
    const int h = blockIdx.y;
    const int kc = blockIdx.x * 64 + w * 16;
    const int qrow = b * S_ + (mha ? SEG2 : SEG1);
    const int krow = b * S_ + (mha ? SEG1 : SEG2);
    const int nk = mha ? NK2 : NK1;
    const int dsl = (lane >> 4) * 8;
    const f32x4 zero = {0.f, 0.f, 0.f, 0.f};

    const bf16x8 kb = *(const bf16x8*)&QK[(size_t)(krow + kc + (lane & 15)) * 2048 + 1024 + h * 32 + dsl];
    const unsigned short* Qp = &QK[(size_t)(qrow + (lane & 15)) * 2048 + h * 32 + dsl];
    const float* iZp = &iZ[(size_t)bm * 2048 + (lane >> 4) * 4];

    float cacc = 0.f;
    for (int qt = 0; qt < 32; ++qt) {
        const unsigned short* p = Qp + (size_t)qt * 64 * 2048;
#pragma unroll
        for (int i = 0; i < 4; ++i) {
            const bf16x8 ai = *(const bf16x8*)(p + (size_t)i * 16 * 2048);
            const f32x4 d = __builtin_amdgcn_mfma_f32_16x16x32_bf16(ai, kb, zero, 0, 0, 0);
            const f32x4 zv = *(const f32x4*)(iZp + qt * 64 + i * 16);
#pragma unroll
            for (int r = 0; r < 4; ++r) cacc += zv[r] * __expf(d[r]);
        }
    }
    cacc += __shfl_xor(cacc, 16, 64);
    cacc += __shfl_xor(cacc, 32, 64);
    if (lane < 16) {
        const int col = kc + lane;
        if (col < nk) CS[((size_t)bm * NH_ + h) * 2048 + col] = cacc;
    }
}

// ---------------------------------------------------------------------------
// Pass C: u[bm][h][c] = sum_k CS[bm][h][k] * X[kbase+k][c]   (fp32, unchanged)
// ---------------------------------------------------------------------------
__global__ __launch_bounds__(256) void colsum_x(
    const float* __restrict__ X, const float* __restrict__ CS,
    float* __restrict__ U)
{
    __shared__ float sl[8][128];
    const int tid = threadIdx.x;
    const int bm = blockIdx.z;
    const int b = bm >> 1, mha = bm & 1;
    const int kbase = mha ? SEG1 : SEG2;
    const int nk = mha ? NK2 : NK1;
    const int kt = blockIdx.x * 128;
    const int hg = blockIdx.y * 8;

    for (int idx = tid; idx < 8 * 128; idx += 256) {
        const int hh = idx >> 7, kk = idx & 127;
        const int k = kt + kk;
        sl[hh][kk] = (k < nk) ? CS[((size_t)bm * NH_ + hg + hh) * 2048 + k] : 0.f;
    }
    __syncthreads();

    float acc[8][4] = {};
    const int c4 = tid * 4;
    for (int kk = 0; kk < 128; ++kk) {
        const int k = kt + kk;
        if (k >= nk) break;  // uniform across block
        const float4 xv = *(const float4*)&X[((size_t)b * S_ + kbase + k) * H_ + c4];
#pragma unroll
        for (int hh = 0; hh < 8; ++hh) {
            const float sv = sl[hh][kk];
            acc[hh][0] += sv * xv.x; acc[hh][1] += sv * xv.y;
            acc[hh][2] += sv * xv.z; acc[hh][3] += sv * xv.w;
        }
    }
#pragma unroll
    for (int hh = 0; hh < 8; ++hh)
#pragma unroll
        for (int c = 0; c < 4; ++c)
            atomicAdd(&U[((size_t)bm * NH_ + hg + hh) * H_ + c4 + c], acc[hh][c]);
}

// ---------------------------------------------------------------------------
__global__ __launch_bounds__(256) void compute_m(
    const float* __restrict__ U, const float* __restrict__ Wv,
    const float* __restrict__ bv, float* __restrict__ Mvec)
{
    const int bm = blockIdx.y;
    const int mha = bm & 1;
    const float invnq = 1.f / (float)(mha ? NQ2 : NQ1);
    const int o = blockIdx.x * 256 + threadIdx.x;
    const int hh = o >> 5;
    const float* u = &U[((size_t)bm * NH_ + hh) * H_];
    const float* w = &Wv[(size_t)o * H_];
    float acc = 0.f;
    for (int in = 0; in < H_; in += 4) {
        const float4 uv = *(const float4*)&u[in];
        const float4 wv = *(const float4*)&w[in];
        acc += uv.x * wv.x + uv.y * wv.y + uv.z * wv.z + uv.w * wv.w;
    }
    Mvec[(size_t)bm * H_ + o] = acc * invnq + bv[o];
}

__global__ __launch_bounds__(256) void final_out(
    const float* __restrict__ Mvec, const float* __restrict__ Wo,
    const float* __restrict__ bo, float* __restrict__ out)
{
    const int bm = blockIdx.y;
    const int b = bm >> 1, mha = bm & 1;
    const int o = blockIdx.x * 256 + threadIdx.x;
    const float* mv = &Mvec[(size_t)bm * H_];
    const float* w = &Wo[(size_t)o * H_];
    float acc = 0.f;
    for (int in = 0; in < H_; in += 4) {
        const float4 mvv = *(const float4*)&mv[in];
        const float4 wv = *(const float4*)&w[in];
        acc += mvv.x * wv.x + mvv.y * wv.y + mvv.z * wv.z + mvv.w * wv.w;
    }
    out[(size_t)b * 2048 + mha * 1024 + o] = acc + bo[o];
}

// ---------------------------------------------------------------------------
extern "C" void kernel_launch(void* const* d_in, const int* in_sizes, int n_in,
                              void* d_out, int out_size, void* d_ws, size_t ws_size,
                              hipStream_t stream)
{
    const float* hidden = (const float*)d_in[0];
    const float* Wq = (const float*)d_in[7];
    const float* bq = (const float*)d_in[8];
    const float* Wk = (const float*)d_in[9];
    const float* bk = (const float*)d_in[10];
    const float* Wv = (const float*)d_in[11];
    const float* bv = (const float*)d_in[12];
    const float* Wo = (const float*)d_in[13];
    const float* bo = (const float*)d_in[14];
    float* out = (float*)d_out;
    char* ws = (char*)d_ws;

    unsigned short* Xb = (unsigned short*)(ws + oXb);
    unsigned short* Wb = (unsigned short*)(ws + oWb);
    float* bb          = (float*)(ws + oBB);
    unsigned short* QK = (unsigned short*)(ws + oQK);
    float* IZ          = (float*)(ws + oIZ);
    float* CS          = (float*)(ws + oCS);
    float* U           = (float*)(ws + oU);
    float* Mv          = (float*)(ws + oMv);

    hipMemsetAsync(U, 0, (size_t)6 * NH_ * H_ * sizeof(float), stream);

    const dim3 blk(256);
    conv_x<<<12288, blk, 0, stream>>>(hidden, Xb);
    conv_w<<<2048, blk, 0, stream>>>(Wq, bq, Wk, bk, Wb, bb);
    proj_mfma<<<dim3(96, 16), blk, 0, stream>>>(Xb, Wb, bb, QK);
    zpass<<<dim3(32, 32, 6), blk, 0, stream>>>(QK, IZ);
    colsum<<<dim3(32, 32, 6), blk, 0, stream>>>(QK, IZ, CS);
    colsum_x<<<dim3(16, 4, 6), blk, 0, stream>>>(hidden, CS, U);
    compute_m<<<dim3(4, 6), blk, 0, stream>>>(U, Wv, bv, Mv);
    final_out<<<dim3(4, 6), blk, 0, stream>>>(Mv, Wo, bo, out);
}

// Round 3
// 537.889 us; speedup vs baseline: 7.7379x; 1.8825x over previous
//
#include <hip/hip_runtime.h>
#include <cstddef>

typedef __attribute__((ext_vector_type(8))) short bf16x8;
typedef __attribute__((ext_vector_type(4))) float f32x4;
typedef __attribute__((ext_vector_type(4))) unsigned short u16x4;
typedef __attribute__((ext_vector_type(8))) unsigned short u16x8;

namespace {
constexpr int B_ = 3, S_ = 4096, H_ = 1024, NH_ = 32;
constexpr int SEG1 = 1, SEG2 = 2049;
constexpr int NQ1 = 2048, NK1 = 2047, NQ2 = 2047, NK2 = 2048;
constexpr float SCALE = 0.17677669529663687f;  // 1/sqrt(32), folded into Wq/bq

// workspace byte offsets (all 16B aligned)
constexpr size_t oXb = 0;                                   // 12288*1024 bf16
constexpr size_t oWb = oXb + (size_t)12288 * 1024 * 2;      // 2048*1024 bf16
constexpr size_t oBB = oWb + (size_t)2048 * 1024 * 2;       // 2048 f32
constexpr size_t oQH = oBB + (size_t)2048 * 4;              // 6*32*2048*32 bf16
constexpr size_t oKH = oQH + (size_t)6 * 32 * 2048 * 32 * 2;
constexpr size_t oIZ = oKH + (size_t)6 * 32 * 2048 * 32 * 2;  // 6*2048 f32
constexpr size_t oCS = oIZ + (size_t)6 * 2048 * 4;          // 6*32*2048 f32
constexpr size_t oU  = oCS + (size_t)6 * 32 * 2048 * 4;     // 6*32*1024 f32
constexpr size_t oMv = oU  + (size_t)6 * 32 * 1024 * 4;     // 6*1024 f32
}

__device__ __forceinline__ unsigned short f2bf(float f) {
    unsigned u = __float_as_uint(f);
    u += 0x7FFF + ((u >> 16) & 1);   // RTNE
    return (unsigned short)(u >> 16);
}

// ---------------------------------------------------------------------------
__global__ __launch_bounds__(256) void conv_x(const float* __restrict__ X,
                                              unsigned short* __restrict__ Xb)
{
    const size_t i4 = (size_t)blockIdx.x * 256 + threadIdx.x;
    const float4 v = *(const float4*)&X[i4 * 4];
    u16x4 o;
    o[0] = f2bf(v.x); o[1] = f2bf(v.y); o[2] = f2bf(v.z); o[3] = f2bf(v.w);
    *(u16x4*)&Xb[i4 * 4] = o;
}

// pack [SCALE*Wq ; Wk] -> bf16, [SCALE*bq ; bk] -> f32
__global__ __launch_bounds__(256) void conv_w(const float* __restrict__ Wq,
                                              const float* __restrict__ bq,
                                              const float* __restrict__ Wk,
                                              const float* __restrict__ bk,
                                              unsigned short* __restrict__ Wb,
                                              float* __restrict__ bb)
{
    const int i4 = blockIdx.x * 256 + threadIdx.x;
    const int base = i4 * 4;
    const bool isQ = base < (1 << 20);
    const float sc = isQ ? SCALE : 1.f;
    const float* src = isQ ? &Wq[base] : &Wk[base - (1 << 20)];
    const float4 v = *(const float4*)src;
    u16x4 o;
    o[0] = f2bf(v.x * sc); o[1] = f2bf(v.y * sc);
    o[2] = f2bf(v.z * sc); o[3] = f2bf(v.w * sc);
    *(u16x4*)&Wb[base] = o;
    if (base < 2048) {
#pragma unroll
        for (int c = 0; c < 4; ++c) {
            const int j = base + c;
            bb[j] = (j < 1024) ? SCALE * bq[j] : bk[j - 1024];
        }
    }
}

// zero the pad rows (idx 2047 of mha1-Q and mha0-K panels)
__global__ __launch_bounds__(256) void zero_pad(unsigned short* __restrict__ QH,
                                                unsigned short* __restrict__ KH)
{
    const int t = blockIdx.x * 256 + threadIdx.x;   // 0..3071
    if (t >= 3072) return;
    const int b = t >> 10, rem = t & 1023, h = rem >> 5, c = rem & 31;
    QH[(((size_t)(b * 2 + 1) * NH_ + h) * 2048 + 2047) * 32 + c] = 0;
    KH[(((size_t)(b * 2 + 0) * NH_ + h) * 2048 + 2047) * 32 + c] = 0;
}

// ---------------------------------------------------------------------------
// Fused Q|K projection -> head-major scatter.
// QH[b2m][h][idx][32] = (X Wq^T + bq)*SCALE ; KH likewise from Wk.
// ---------------------------------------------------------------------------
__global__ __launch_bounds__(256) void proj_mfma(const unsigned short* __restrict__ Xb,
                                                 const unsigned short* __restrict__ Wb,
                                                 const float* __restrict__ bb,
                                                 unsigned short* __restrict__ QH,
                                                 unsigned short* __restrict__ KH)
{
    __shared__ unsigned short lds[2 * 128 * 40];   // A then B, pitch 40 ushorts = 80B
    const int tid = threadIdx.x;
    const int lane = tid & 63, w = tid >> 6;
    const int m0 = blockIdx.x * 128, n0 = blockIdx.y * 128;
    const int wr = (w >> 1) * 64, wc = (w & 1) * 64;
    const int Gr = tid >> 2, Gg = tid & 3;

    const unsigned short* gA = &Xb[(size_t)(m0 + Gr) * 1024 + Gg * 8];
    const unsigned short* gB = &Wb[(size_t)(n0 + Gr) * 1024 + Gg * 8];
    unsigned short* sA = &lds[Gr * 40 + Gg * 8];
    unsigned short* sB = &lds[128 * 40 + Gr * 40 + Gg * 8];
    const unsigned short* fA = &lds[(wr + (lane & 15)) * 40 + (lane >> 4) * 8];
    const unsigned short* fB = &lds[128 * 40 + (wc + (lane & 15)) * 40 + (lane >> 4) * 8];

    f32x4 acc[4][4] = {};
    u16x8 rA0 = *(const u16x8*)(gA);
    u16x8 rA1 = *(const u16x8*)(gA + 64 * 1024);
    u16x8 rB0 = *(const u16x8*)(gB);
    u16x8 rB1 = *(const u16x8*)(gB + 64 * 1024);

    for (int k0 = 0; k0 < 1024; k0 += 32) {
        __syncthreads();
        *(u16x8*)(sA) = rA0; *(u16x8*)(sA + 64 * 40) = rA1;
        *(u16x8*)(sB) = rB0; *(u16x8*)(sB + 64 * 40) = rB1;
        __syncthreads();
        if (k0 + 32 < 1024) {
            rA0 = *(const u16x8*)(gA + k0 + 32);
            rA1 = *(const u16x8*)(gA + 64 * 1024 + k0 + 32);
            rB0 = *(const u16x8*)(gB + k0 + 32);
            rB1 = *(const u16x8*)(gB + 64 * 1024 + k0 + 32);
        }
        bf16x8 a[4], b[4];
#pragma unroll
        for (int i = 0; i < 4; ++i) a[i] = *(const bf16x8*)(fA + i * 16 * 40);
#pragma unroll
        for (int j = 0; j < 4; ++j) b[j] = *(const bf16x8*)(fB + j * 16 * 40);
#pragma unroll
        for (int i = 0; i < 4; ++i)
#pragma unroll
            for (int j = 0; j < 4; ++j)
                acc[i][j] = __builtin_amdgcn_mfma_f32_16x16x32_bf16(a[i], b[j], acc[i][j], 0, 0, 0);
    }

    // epilogue: head-major scatter. Block is entirely Q-side or K-side.
    const bool sideK = (n0 >= 1024);
    unsigned short* dst = sideK ? KH : QH;

    // per-(i,r) row offset (in ushorts) into dst, -1 if row unused
    int rowoff[4][4];
#pragma unroll
    for (int i = 0; i < 4; ++i)
#pragma unroll
        for (int r = 0; r < 4; ++r) {
            const int g = m0 + wr + 16 * i + (lane >> 4) * 4 + r;
            const int b = g >> 12, rr = g & 4095;
            int v = -1;
            if (rr >= 2049) {
                const int seg = b * 2 + (sideK ? 0 : 1);
                v = seg * (NH_ * 2048 * 32) + (rr - 2049) * 32;
            } else if (rr >= 1) {
                const int seg = b * 2 + (sideK ? 1 : 0);
                v = seg * (NH_ * 2048 * 32) + (rr - 1) * 32;
            }
            rowoff[i][r] = v;
        }

#pragma unroll
    for (int j = 0; j < 4; ++j) {
        const int col = n0 + wc + 16 * j + (lane & 15);
        const float bias = bb[col];
        const int cs = col - (sideK ? 1024 : 0);
        const int coloff = (cs >> 5) * (2048 * 32) + (cs & 31);
#pragma unroll
        for (int i = 0; i < 4; ++i)
#pragma unroll
            for (int r = 0; r < 4; ++r)
                if (rowoff[i][r] >= 0)
                    dst[(size_t)rowoff[i][r] + coloff] = f2bf(acc[i][j][r] + bias);
    }
}

// ---------------------------------------------------------------------------
// Pass 1: iZ[bm][q] = 1 / sum_k exp(s[q][k]).
// grid (8, 32 heads, 6 bm); each wave owns 64 q rows (4 A-fragments), streams K.
// ---------------------------------------------------------------------------
__global__ __launch_bounds__(256) void zpass(const unsigned short* __restrict__ QH,
                                             const unsigned short* __restrict__ KH,
                                             float* __restrict__ iZ)
{
    const int tid = threadIdx.x, lane = tid & 63, w = tid >> 6;
    const int bm = blockIdx.z, mha = bm & 1;
    const int h = blockIdx.y;
    const int nq = mha ? NQ2 : NQ1, nk = mha ? NK2 : NK1;
    const size_t panel = ((size_t)bm * NH_ + h) * 2048 * 32;
    const int lr = lane & 15, lg = lane >> 4;
    const int q0 = blockIdx.x * 256 + w * 64;
    const f32x4 zero = {0.f, 0.f, 0.f, 0.f};

    const unsigned short* Qp = QH + panel + (size_t)(q0 + lr) * 32 + lg * 8;
    const unsigned short* Kp = KH + panel + (size_t)lr * 32 + lg * 8;

    bf16x8 a[4];
#pragma unroll
    for (int i = 0; i < 4; ++i) a[i] = *(const bf16x8*)(Qp + i * 16 * 32);

    float z[4][4] = {};
    for (int kt = 0; kt < 127; ++kt) {
        const bf16x8 kb = *(const bf16x8*)(Kp + (size_t)kt * 16 * 32);
#pragma unroll
        for (int i = 0; i < 4; ++i) {
            const f32x4 d = __builtin_amdgcn_mfma_f32_16x16x32_bf16(a[i], kb, zero, 0, 0, 0);
#pragma unroll
            for (int r = 0; r < 4; ++r) z[i][r] += __expf(d[r]);
        }
    }
    {   // tail k-tile with column mask (masks pad col 2047 for mha0)
        const bf16x8 kb = *(const bf16x8*)(Kp + (size_t)127 * 16 * 32);
        const float m = (2032 + lr < nk) ? 1.f : 0.f;
#pragma unroll
        for (int i = 0; i < 4; ++i) {
            const f32x4 d = __builtin_amdgcn_mfma_f32_16x16x32_bf16(a[i], kb, zero, 0, 0, 0);
#pragma unroll
            for (int r = 0; r < 4; ++r) z[i][r] += m * __expf(d[r]);
        }
    }

#pragma unroll
    for (int i = 0; i < 4; ++i) {
#pragma unroll
        for (int r = 0; r < 4; ++r) {
            float v = z[i][r];
            v += __shfl_xor(v, 1, 64);
            v += __shfl_xor(v, 2, 64);
            v += __shfl_xor(v, 4, 64);
            v += __shfl_xor(v, 8, 64);
            z[i][r] = v;
        }
        if (lr == 0) {
            const int qb = q0 + i * 16 + lg * 4;
            f32x4 o;
#pragma unroll
            for (int r = 0; r < 4; ++r)
                o[r] = (qb + r < nq) ? 1.f / z[i][r] : 0.f;  // 0 masks pad q rows
            *(f32x4*)&iZ[(size_t)bm * 2048 + qb] = o;
        }
    }
}

// ---------------------------------------------------------------------------
// Pass 2: CS[bm][h][k] = sum_q exp(s[q][k]) * iZ[q].
// grid (8, 32, 6); each wave owns 64 k cols (4 B-fragments), streams Q.
// ---------------------------------------------------------------------------
__global__ __launch_bounds__(256) void colsum(const unsigned short* __restrict__ QH,
                                              const unsigned short* __restrict__ KH,
                                              const float* __restrict__ iZ,
                                              float* __restrict__ CS)
{
    const int tid = threadIdx.x, lane = tid & 63, w = tid >> 6;
    const int bm = blockIdx.z, mha = bm & 1;
    const int h = blockIdx.y;
    const int nk = mha ? NK2 : NK1;
    const size_t panel = ((size_t)bm * NH_ + h) * 2048 * 32;
    const int lr = lane & 15, lg = lane >> 4;
    const int kc = blockIdx.x * 256 + w * 64;
    const f32x4 zero = {0.f, 0.f, 0.f, 0.f};

    const unsigned short* Kp = KH + panel + (size_t)(kc + lr) * 32 + lg * 8;
    const unsigned short* Qp = QH + panel + (size_t)lr * 32 + lg * 8;
    const float* zp = iZ + (size_t)bm * 2048 + lg * 4;

    bf16x8 kb[4];
#pragma unroll
    for (int j = 0; j < 4; ++j) kb[j] = *(const bf16x8*)(Kp + j * 16 * 32);

    float cacc[4] = {};
    for (int qt = 0; qt < 128; ++qt) {
        const bf16x8 ai = *(const bf16x8*)(Qp + (size_t)qt * 16 * 32);
        const f32x4 zv = *(const f32x4*)(zp + qt * 16);
#pragma unroll
        for (int j = 0; j < 4; ++j) {
            const f32x4 d = __builtin_amdgcn_mfma_f32_16x16x32_bf16(ai, kb[j], zero, 0, 0, 0);
#pragma unroll
            for (int r = 0; r < 4; ++r) cacc[j] += zv[r] * __expf(d[r]);
        }
    }

#pragma unroll
    for (int j = 0; j < 4; ++j) {
        float v = cacc[j];
        v += __shfl_xor(v, 16, 64);
        v += __shfl_xor(v, 32, 64);
        const int col = kc + 16 * j + lr;
        if (lane < 16 && col < nk)
            CS[((size_t)bm * NH_ + h) * 2048 + col] = v;
    }
}

// ---------------------------------------------------------------------------
// Pass C: u[bm][h][c] = sum_k CS[bm][h][k] * X[kbase+k][c]   (fp32)
// ---------------------------------------------------------------------------
__global__ __launch_bounds__(256) void colsum_x(
    const float* __restrict__ X, const float* __restrict__ CS,
    float* __restrict__ U)
{
    __shared__ float sl[8][128];
    const int tid = threadIdx.x;
    const int bm = blockIdx.z;
    const int b = bm >> 1, mha = bm & 1;
    const int kbase = mha ? SEG1 : SEG2;
    const int nk = mha ? NK2 : NK1;
    const int kt = blockIdx.x * 128;
    const int hg = blockIdx.y * 8;

    for (int idx = tid; idx < 8 * 128; idx += 256) {
        const int hh = idx >> 7, kk = idx & 127;
        const int k = kt + kk;
        sl[hh][kk] = (k < nk) ? CS[((size_t)bm * NH_ + hg + hh) * 2048 + k] : 0.f;
    }
    __syncthreads();

    float acc[8][4] = {};
    const int c4 = tid * 4;
    for (int kk = 0; kk < 128; ++kk) {
        const int k = kt + kk;
        if (k >= nk) break;
        const float4 xv = *(const float4*)&X[((size_t)b * S_ + kbase + k) * H_ + c4];
#pragma unroll
        for (int hh = 0; hh < 8; ++hh) {
            const float sv = sl[hh][kk];
            acc[hh][0] += sv * xv.x; acc[hh][1] += sv * xv.y;
            acc[hh][2] += sv * xv.z; acc[hh][3] += sv * xv.w;
        }
    }
#pragma unroll
    for (int hh = 0; hh < 8; ++hh)
#pragma unroll
        for (int c = 0; c < 4; ++c)
            atomicAdd(&U[((size_t)bm * NH_ + hg + hh) * H_ + c4 + c], acc[hh][c]);
}

// ---------------------------------------------------------------------------
__global__ __launch_bounds__(256) void compute_m(
    const float* __restrict__ U, const float* __restrict__ Wv,
    const float* __restrict__ bv, float* __restrict__ Mvec)
{
    const int bm = blockIdx.y;
    const int mha = bm & 1;
    const float invnq = 1.f / (float)(mha ? NQ2 : NQ1);
    const int o = blockIdx.x * 256 + threadIdx.x;
    const int hh = o >> 5;
    const float* u = &U[((size_t)bm * NH_ + hh) * H_];
    const float* w = &Wv[(size_t)o * H_];
    float acc = 0.f;
    for (int in = 0; in < H_; in += 4) {
        const float4 uv = *(const float4*)&u[in];
        const float4 wv = *(const float4*)&w[in];
        acc += uv.x * wv.x + uv.y * wv.y + uv.z * wv.z + uv.w * wv.w;
    }
    Mvec[(size_t)bm * H_ + o] = acc * invnq + bv[o];
}

__global__ __launch_bounds__(256) void final_out(
    const float* __restrict__ Mvec, const float* __restrict__ Wo,
    const float* __restrict__ bo, float* __restrict__ out)
{
    const int bm = blockIdx.y;
    const int b = bm >> 1, mha = bm & 1;
    const int o = blockIdx.x * 256 + threadIdx.x;
    const float* mv = &Mvec[(size_t)bm * H_];
    const float* w = &Wo[(size_t)o * H_];
    float acc = 0.f;
    for (int in = 0; in < H_; in += 4) {
        const float4 mvv = *(const float4*)&mv[in];
        const float4 wv = *(const float4*)&w[in];
        acc += mvv.x * wv.x + mvv.y * wv.y + mvv.z * wv.z + mvv.w * wv.w;
    }
    out[(size_t)b * 2048 + mha * 1024 + o] = acc + bo[o];
}

// ---------------------------------------------------------------------------
extern "C" void kernel_launch(void* const* d_in, const int* in_sizes, int n_in,
                              void* d_out, int out_size, void* d_ws, size_t ws_size,
                              hipStream_t stream)
{
    const float* hidden = (const float*)d_in[0];
    const float* Wq = (const float*)d_in[7];
    const float* bq = (const float*)d_in[8];
    const float* Wk = (const float*)d_in[9];
    const float* bk = (const float*)d_in[10];
    const float* Wv = (const float*)d_in[11];
    const float* bv = (const float*)d_in[12];
    const float* Wo = (const float*)d_in[13];
    const float* bo = (const float*)d_in[14];
    float* out = (float*)d_out;
    char* ws = (char*)d_ws;

    unsigned short* Xb = (unsigned short*)(ws + oXb);
    unsigned short* Wb = (unsigned short*)(ws + oWb);
    float* bb          = (float*)(ws + oBB);
    unsigned short* QHp = (unsigned short*)(ws + oQH);
    unsigned short* KHp = (unsigned short*)(ws + oKH);
    float* IZ          = (float*)(ws + oIZ);
    float* CS          = (float*)(ws + oCS);
    float* U           = (float*)(ws + oU);
    float* Mv          = (float*)(ws + oMv);

    hipMemsetAsync(U, 0, (size_t)6 * NH_ * H_ * sizeof(float), stream);

    const dim3 blk(256);
    conv_x<<<12288, blk, 0, stream>>>(hidden, Xb);
    conv_w<<<2048, blk, 0, stream>>>(Wq, bq, Wk, bk, Wb, bb);
    zero_pad<<<12, blk, 0, stream>>>(QHp, KHp);
    proj_mfma<<<dim3(96, 16), blk, 0, stream>>>(Xb, Wb, bb, QHp, KHp);
    zpass<<<dim3(8, 32, 6), blk, 0, stream>>>(QHp, KHp, IZ);
    colsum<<<dim3(8, 32, 6), blk, 0, stream>>>(QHp, KHp, IZ, CS);
    colsum_x<<<dim3(16, 4, 6), blk, 0, stream>>>(hidden, CS, U);
    compute_m<<<dim3(4, 6), blk, 0, stream>>>(U, Wv, bv, Mv);
    final_out<<<dim3(4, 6), blk, 0, stream>>>(Mv, Wo, bo, out);
}

// Round 5
// 528.443 us; speedup vs baseline: 7.8762x; 1.0179x over previous
//
#include <hip/hip_runtime.h>
#include <cstddef>

typedef __attribute__((ext_vector_type(8))) short bf16x8;
typedef __attribute__((ext_vector_type(4))) float f32x4;
typedef __attribute__((ext_vector_type(4))) unsigned short u16x4;
typedef __attribute__((ext_vector_type(8))) unsigned short u16x8;

namespace {
constexpr int B_ = 3, S_ = 4096, H_ = 1024, NH_ = 32;
constexpr int SEG1 = 1, SEG2 = 2049;
constexpr int NQ1 = 2048, NK1 = 2047, NQ2 = 2047, NK2 = 2048;
constexpr float SCALE = 0.17677669529663687f;              // 1/sqrt(32)
constexpr float LOG2E = 1.4426950408889634f;
constexpr float QSC   = SCALE * LOG2E;                     // folded into Wq/bq

// workspace byte offsets (all 16B aligned)
constexpr size_t oXb = 0;                                   // 12288*1024 bf16
constexpr size_t oWb = oXb + (size_t)12288 * 1024 * 2;      // 2048*1024 bf16
constexpr size_t oBB = oWb + (size_t)2048 * 1024 * 2;       // 2048 f32
constexpr size_t oQH = oBB + (size_t)2048 * 4;              // 6*32*2048*32 bf16
constexpr size_t oKH = oQH + (size_t)6 * 32 * 2048 * 32 * 2;
constexpr size_t oNL = oKH + (size_t)6 * 32 * 2048 * 32 * 2;  // negL 6*2048 f32
constexpr size_t oCS = oNL + (size_t)6 * 2048 * 4;          // 6*32*2048 f32
constexpr size_t oU  = oCS + (size_t)6 * 32 * 2048 * 4;     // 6*32*1024 f32
constexpr size_t oMv = oU  + (size_t)6 * 32 * 1024 * 4;     // 6*1024 f32
}

#if __has_builtin(__builtin_amdgcn_exp2f)
#define EXP2(x) __builtin_amdgcn_exp2f(x)
#else
#define EXP2(x) exp2f(x)
#endif
#if __has_builtin(__builtin_amdgcn_logf)
#define LOG2(x) __builtin_amdgcn_logf(x)
#else
#define LOG2(x) log2f(x)
#endif

__device__ __forceinline__ unsigned short f2bf(float f) {
    unsigned u = __float_as_uint(f);
    u += 0x7FFF + ((u >> 16) & 1);   // RTNE
    return (unsigned short)(u >> 16);
}
__device__ __forceinline__ float bf2f(unsigned short u) {
    return __uint_as_float((unsigned)u << 16);
}
__device__ __forceinline__ void gl16(const unsigned short* gp, unsigned short* lp) {
    __builtin_amdgcn_global_load_lds(
        (const __attribute__((address_space(1))) unsigned int*)gp,
        (__attribute__((address_space(3))) unsigned int*)lp, 16, 0, 0);
}

// ---------------------------------------------------------------------------
__global__ __launch_bounds__(256) void conv_x(const float* __restrict__ X,
                                              unsigned short* __restrict__ Xb)
{
    const size_t i4 = (size_t)blockIdx.x * 256 + threadIdx.x;
    const float4 v = *(const float4*)&X[i4 * 4];
    u16x4 o;
    o[0] = f2bf(v.x); o[1] = f2bf(v.y); o[2] = f2bf(v.z); o[3] = f2bf(v.w);
    *(u16x4*)&Xb[i4 * 4] = o;
}

// pack [QSC*Wq ; Wk] -> bf16, [QSC*bq ; bk] -> f32; also zero pad rows of QH/KH
__global__ __launch_bounds__(256) void conv_w(const float* __restrict__ Wq,
                                              const float* __restrict__ bq,
                                              const float* __restrict__ Wk,
                                              const float* __restrict__ bk,
                                              unsigned short* __restrict__ Wb,
                                              float* __restrict__ bb,
                                              unsigned short* __restrict__ QH,
                                              unsigned short* __restrict__ KH)
{
    const int i4 = blockIdx.x * 256 + threadIdx.x;
    const int base = i4 * 4;
    const bool isQ = base < (1 << 20);
    const float sc = isQ ? QSC : 1.f;
    const float* src = isQ ? &Wq[base] : &Wk[base - (1 << 20)];
    const float4 v = *(const float4*)src;
    u16x4 o;
    o[0] = f2bf(v.x * sc); o[1] = f2bf(v.y * sc);
    o[2] = f2bf(v.z * sc); o[3] = f2bf(v.w * sc);
    *(u16x4*)&Wb[base] = o;
    if (base < 2048) {
#pragma unroll
        for (int c = 0; c < 4; ++c) {
            const int j = base + c;
            bb[j] = (j < 1024) ? QSC * bq[j] : bk[j - 1024];
        }
    }
    if (i4 < 3072) {   // zero pad rows (idx 2047 of mha1-Q and mha0-K panels)
        const int b = i4 >> 10, rem = i4 & 1023, h = rem >> 5, c = rem & 31;
        QH[(((size_t)(b * 2 + 1) * NH_ + h) * 2048 + 2047) * 32 + c] = 0;
        KH[(((size_t)(b * 2 + 0) * NH_ + h) * 2048 + 2047) * 32 + c] = 0;
    }
}

// ---------------------------------------------------------------------------
// Fused Q|K projection -> head-major scatter.
// global_load_lds (16B) staging, double-buffered, XOR-swizzled granules.
// ---------------------------------------------------------------------------
__global__ __launch_bounds__(256) void proj_mfma(const unsigned short* __restrict__ Xb,
                                                 const unsigned short* __restrict__ Wb,
                                                 const float* __restrict__ bb,
                                                 unsigned short* __restrict__ QH,
                                                 unsigned short* __restrict__ KH)
{
    __shared__ unsigned short ldsA[2][4096];   // [buf][128 rows * 32 (=BK)]
    __shared__ unsigned short ldsB[2][4096];
    const int tid = threadIdx.x;
    const int lane = tid & 63, w = tid >> 6;
    const int m0 = blockIdx.x * 128, n0 = blockIdx.y * 128;
    const int wr = (w >> 1) * 64, wc = (w & 1) * 64;

    // staging: lane -> row (lane>>2), granule pre-swizzled g ^ ((row>>1)&3)
    const int co = ((lane & 3) ^ ((lane >> 3) & 3)) * 8;
    const unsigned short* gAl = Xb + (size_t)(m0 + 32 * w + (lane >> 2)) * 1024 + co;
    const unsigned short* gBl = Wb + (size_t)(n0 + 32 * w + (lane >> 2)) * 1024 + co;

#define STAGE(K0, BUF) do { \
    gl16(gAl + (K0),             &ldsA[BUF][(32 * w) * 32]); \
    gl16(gAl + (K0) + 16 * 1024, &ldsA[BUF][(32 * w + 16) * 32]); \
    gl16(gBl + (K0),             &ldsB[BUF][(32 * w) * 32]); \
    gl16(gBl + (K0) + 16 * 1024, &ldsB[BUF][(32 * w + 16) * 32]); \
} while (0)

    // fragment read offsets (apply the same XOR on the read side)
    const int mrA = wr + (lane & 15);
    const int mrB = wc + (lane & 15);
    const int gg = lane >> 4;
    const int oA = mrA * 32 + ((gg ^ ((mrA >> 1) & 3)) * 8);
    const int oB = mrB * 32 + ((gg ^ ((mrB >> 1) & 3)) * 8);

    f32x4 acc[4][4] = {};
    STAGE(0, 0);
    asm volatile("s_waitcnt vmcnt(0)" ::: "memory");
    __syncthreads();

    for (int kt = 0; kt < 32; ++kt) {
        const int buf = kt & 1;
        if (kt < 31) STAGE((kt + 1) * 32, buf ^ 1);
        bf16x8 a[4], b[4];
#pragma unroll
        for (int i = 0; i < 4; ++i) a[i] = *(const bf16x8*)&ldsA[buf][oA + i * 512];
#pragma unroll
        for (int j = 0; j < 4; ++j) b[j] = *(const bf16x8*)&ldsB[buf][oB + j * 512];
#pragma unroll
        for (int i = 0; i < 4; ++i)
#pragma unroll
            for (int j = 0; j < 4; ++j)
                acc[i][j] = __builtin_amdgcn_mfma_f32_16x16x32_bf16(a[i], b[j], acc[i][j], 0, 0, 0);
        asm volatile("s_waitcnt vmcnt(0)" ::: "memory");
        __syncthreads();
    }
#undef STAGE

    // epilogue: head-major scatter. Block is entirely Q-side or K-side.
    const bool sideK = (n0 >= 1024);
    unsigned short* dst = sideK ? KH : QH;

    int rowoff[4][4];
#pragma unroll
    for (int i = 0; i < 4; ++i)
#pragma unroll
        for (int r = 0; r < 4; ++r) {
            const int g = m0 + wr + 16 * i + (lane >> 4) * 4 + r;
            const int b = g >> 12, rr = g & 4095;
            int v = -1;
            if (rr >= 2049) {
                const int seg = b * 2 + (sideK ? 0 : 1);
                v = seg * (NH_ * 2048 * 32) + (rr - 2049) * 32;
            } else if (rr >= 1) {
                const int seg = b * 2 + (sideK ? 1 : 0);
                v = seg * (NH_ * 2048 * 32) + (rr - 1) * 32;
            }
            rowoff[i][r] = v;
        }

#pragma unroll
    for (int j = 0; j < 4; ++j) {
        const int col = n0 + wc + 16 * j + (lane & 15);
        const float bias = bb[col];
        const int cs = col - (sideK ? 1024 : 0);
        const int coloff = (cs >> 5) * (2048 * 32) + (cs & 31);
#pragma unroll
        for (int i = 0; i < 4; ++i)
#pragma unroll
            for (int r = 0; r < 4; ++r)
                if (rowoff[i][r] >= 0)
                    dst[(size_t)rowoff[i][r] + coloff] = f2bf(acc[i][j][r] + bias);
    }
}

// ---------------------------------------------------------------------------
// Pass 1: negL[bm][q] = -log2( sum_k exp2(s2[q][k]) ), s2 = log2-domain score.
// grid (8, 32 heads, 6 bm); each wave owns 64 q rows (4 A-frags), streams K.
// ---------------------------------------------------------------------------
__global__ __launch_bounds__(256) void zpass(const unsigned short* __restrict__ QH,
                                             const unsigned short* __restrict__ KH,
                                             float* __restrict__ NL)
{
    const int tid = threadIdx.x, lane = tid & 63, w = tid >> 6;
    const int bm = blockIdx.z, mha = bm & 1;
    const int h = blockIdx.y;
    const int nq = mha ? NQ2 : NQ1, nk = mha ? NK2 : NK1;
    const size_t panel = ((size_t)bm * NH_ + h) * 2048 * 32;
    const int lr = lane & 15, lg = lane >> 4;
    const int q0 = blockIdx.x * 256 + w * 64;
    const f32x4 zero = {0.f, 0.f, 0.f, 0.f};

    const unsigned short* Qp = QH + panel + (size_t)(q0 + lr) * 32 + lg * 8;
    const unsigned short* Kp = KH + panel + (size_t)lr * 32 + lg * 8;

    bf16x8 a[4];
#pragma unroll
    for (int i = 0; i < 4; ++i) a[i] = *(const bf16x8*)(Qp + i * 16 * 32);

    float z[4][4] = {};
    for (int kt = 0; kt < 127; ++kt) {
        const bf16x8 kb = *(const bf16x8*)(Kp + (size_t)kt * 16 * 32);
#pragma unroll
        for (int i = 0; i < 4; ++i) {
            const f32x4 d = __builtin_amdgcn_mfma_f32_16x16x32_bf16(a[i], kb, zero, 0, 0, 0);
#pragma unroll
            for (int r = 0; r < 4; ++r) z[i][r] += EXP2(d[r]);
        }
    }
    {   // tail k-tile with column mask (masks pad col 2047 for mha0)
        const bf16x8 kb = *(const bf16x8*)(Kp + (size_t)127 * 16 * 32);
        const float m = (2032 + lr < nk) ? 1.f : 0.f;
#pragma unroll
        for (int i = 0; i < 4; ++i) {
            const f32x4 d = __builtin_amdgcn_mfma_f32_16x16x32_bf16(a[i], kb, zero, 0, 0, 0);
#pragma unroll
            for (int r = 0; r < 4; ++r) z[i][r] += m * EXP2(d[r]);
        }
    }

#pragma unroll
    for (int i = 0; i < 4; ++i) {
#pragma unroll
        for (int r = 0; r < 4; ++r) {
            float v = z[i][r];
            v += __shfl_xor(v, 1, 64);
            v += __shfl_xor(v, 2, 64);
            v += __shfl_xor(v, 4, 64);
            v += __shfl_xor(v, 8, 64);
            z[i][r] = v;
        }
        if (lr == 0) {
            const int qb = q0 + i * 16 + lg * 4;
            f32x4 o;
#pragma unroll
            for (int r = 0; r < 4; ++r)
                o[r] = (qb + r < nq) ? -LOG2(z[i][r]) : -1e30f;  // -inf masks pad q
            *(f32x4*)&NL[(size_t)bm * 2048 + qb] = o;
        }
    }
}

// ---------------------------------------------------------------------------
// Pass 2: CS[bm][h][k] = sum_q exp2(s2[q][k] + negL[q]).  negL rides in the
// MFMA accumulator (per-output-row constant), so per score = exp2 + add.
// ---------------------------------------------------------------------------
__global__ __launch_bounds__(256) void colsum(const unsigned short* __restrict__ QH,
                                              const unsigned short* __restrict__ KH,
                                              const float* __restrict__ NL,
                                              float* __restrict__ CS)
{
    const int tid = threadIdx.x, lane = tid & 63, w = tid >> 6;
    const int bm = blockIdx.z, mha = bm & 1;
    const int h = blockIdx.y;
    const int nk = mha ? NK2 : NK1;
    const size_t panel = ((size_t)bm * NH_ + h) * 2048 * 32;
    const int lr = lane & 15, lg = lane >> 4;
    const int kc = blockIdx.x * 256 + w * 64;

    const unsigned short* Kp = KH + panel + (size_t)(kc + lr) * 32 + lg * 8;
    const unsigned short* Qp = QH + panel + (size_t)lr * 32 + lg * 8;
    const float* zp = NL + (size_t)bm * 2048 + lg * 4;

    bf16x8 kb[4];
#pragma unroll
    for (int j = 0; j < 4; ++j) kb[j] = *(const bf16x8*)(Kp + j * 16 * 32);

    float cacc[4] = {};
    for (int qt = 0; qt < 128; ++qt) {
        const bf16x8 ai = *(const bf16x8*)(Qp + (size_t)qt * 16 * 32);
        const f32x4 cv = *(const f32x4*)(zp + qt * 16);
#pragma unroll
        for (int j = 0; j < 4; ++j) {
            const f32x4 d = __builtin_amdgcn_mfma_f32_16x16x32_bf16(ai, kb[j], cv, 0, 0, 0);
#pragma unroll
            for (int r = 0; r < 4; ++r) cacc[j] += EXP2(d[r]);
        }
    }

#pragma unroll
    for (int j = 0; j < 4; ++j) {
        float v = cacc[j];
        v += __shfl_xor(v, 16, 64);
        v += __shfl_xor(v, 32, 64);
        const int col = kc + 16 * j + lr;
        if (lane < 16 && col < nk)
            CS[((size_t)bm * NH_ + h) * 2048 + col] = v;
    }
}

// ---------------------------------------------------------------------------
// Pass C: u[bm][h][c] = sum_k CS[bm][h][k] * Xb[kbase+k][c]   (bf16 X)
// grid (32 ktiles of 64, 4 headgroups, 6 bm)
// ---------------------------------------------------------------------------
__global__ __launch_bounds__(256) void colsum_x(
    const unsigned short* __restrict__ Xb, const float* __restrict__ CS,
    float* __restrict__ U)
{
    __shared__ float sl[8][64];
    const int tid = threadIdx.x;
    const int bm = blockIdx.z;
    const int b = bm >> 1, mha = bm & 1;
    const int kbase = mha ? SEG1 : SEG2;
    const int nk = mha ? NK2 : NK1;
    const int kt = blockIdx.x * 64;
    const int hg = blockIdx.y * 8;

    for (int idx = tid; idx < 8 * 64; idx += 256) {   // FIX: full 512-entry fill
        const int hh = idx >> 6, kk = idx & 63;
        const int k = kt + kk;
        sl[hh][kk] = (k < nk) ? CS[((size_t)bm * NH_ + hg + hh) * 2048 + k] : 0.f;
    }
    __syncthreads();

    float acc[8][4] = {};
    const int c4 = tid * 4;
    for (int kk = 0; kk < 64; ++kk) {
        const int k = kt + kk;
        if (k >= nk) break;   // uniform across block
        const u16x4 xv = *(const u16x4*)&Xb[((size_t)b * S_ + kbase + k) * H_ + c4];
        const float x0 = bf2f(xv[0]), x1 = bf2f(xv[1]), x2 = bf2f(xv[2]), x3 = bf2f(xv[3]);
#pragma unroll
        for (int hh = 0; hh < 8; ++hh) {
            const float sv = sl[hh][kk];
            acc[hh][0] += sv * x0; acc[hh][1] += sv * x1;
            acc[hh][2] += sv * x2; acc[hh][3] += sv * x3;
        }
    }
#pragma unroll
    for (int hh = 0; hh < 8; ++hh)
#pragma unroll
        for (int c = 0; c < 4; ++c)
            atomicAdd(&U[((size_t)bm * NH_ + hg + hh) * H_ + c4 + c], acc[hh][c]);
}

// ---------------------------------------------------------------------------
__global__ __launch_bounds__(256) void compute_m(
    const float* __restrict__ U, const float* __restrict__ Wv,
    const float* __restrict__ bv, float* __restrict__ Mvec)
{
    const int bm = blockIdx.y;
    const int mha = bm & 1;
    const float invnq = 1.f / (float)(mha ? NQ2 : NQ1);
    const int o = blockIdx.x * 256 + threadIdx.x;
    const int hh = o >> 5;
    const float* u = &U[((size_t)bm * NH_ + hh) * H_];
    const float* w = &Wv[(size_t)o * H_];
    float acc = 0.f;
    for (int in = 0; in < H_; in += 4) {
        const float4 uv = *(const float4*)&u[in];
        const float4 wv = *(const float4*)&w[in];
        acc += uv.x * wv.x + uv.y * wv.y + uv.z * wv.z + uv.w * wv.w;
    }
    Mvec[(size_t)bm * H_ + o] = acc * invnq + bv[o];
}

__global__ __launch_bounds__(256) void final_out(
    const float* __restrict__ Mvec, const float* __restrict__ Wo,
    const float* __restrict__ bo, float* __restrict__ out)
{
    const int bm = blockIdx.y;
    const int b = bm >> 1, mha = bm & 1;
    const int o = blockIdx.x * 256 + threadIdx.x;
    const float* mv = &Mvec[(size_t)bm * H_];
    const float* w = &Wo[(size_t)o * H_];
    float acc = 0.f;
    for (int in = 0; in < H_; in += 4) {
        const float4 mvv = *(const float4*)&mv[in];
        const float4 wv = *(const float4*)&w[in];
        acc += mvv.x * wv.x + mvv.y * wv.y + mvv.z * wv.z + mvv.w * wv.w;
    }
    out[(size_t)b * 2048 + mha * 1024 + o] = acc + bo[o];
}

// ---------------------------------------------------------------------------
extern "C" void kernel_launch(void* const* d_in, const int* in_sizes, int n_in,
                              void* d_out, int out_size, void* d_ws, size_t ws_size,
                              hipStream_t stream)
{
    const float* hidden = (const float*)d_in[0];
    const float* Wq = (const float*)d_in[7];
    const float* bq = (const float*)d_in[8];
    const float* Wk = (const float*)d_in[9];
    const float* bk = (const float*)d_in[10];
    const float* Wv = (const float*)d_in[11];
    const float* bv = (const float*)d_in[12];
    const float* Wo = (const float*)d_in[13];
    const float* bo = (const float*)d_in[14];
    float* out = (float*)d_out;
    char* ws = (char*)d_ws;

    unsigned short* Xb  = (unsigned short*)(ws + oXb);
    unsigned short* Wb  = (unsigned short*)(ws + oWb);
    float* bb           = (float*)(ws + oBB);
    unsigned short* QHp = (unsigned short*)(ws + oQH);
    unsigned short* KHp = (unsigned short*)(ws + oKH);
    float* NL           = (float*)(ws + oNL);
    float* CS           = (float*)(ws + oCS);
    float* U            = (float*)(ws + oU);
    float* Mv           = (float*)(ws + oMv);

    hipMemsetAsync(U, 0, (size_t)6 * NH_ * H_ * sizeof(float), stream);

    const dim3 blk(256);
    conv_x<<<12288, blk, 0, stream>>>(hidden, Xb);
    conv_w<<<2048, blk, 0, stream>>>(Wq, bq, Wk, bk, Wb, bb, QHp, KHp);
    proj_mfma<<<dim3(96, 16), blk, 0, stream>>>(Xb, Wb, bb, QHp, KHp);
    zpass<<<dim3(8, 32, 6), blk, 0, stream>>>(QHp, KHp, NL);
    colsum<<<dim3(8, 32, 6), blk, 0, stream>>>(QHp, KHp, NL, CS);
    colsum_x<<<dim3(32, 4, 6), blk, 0, stream>>>(Xb, CS, U);
    compute_m<<<dim3(4, 6), blk, 0, stream>>>(U, Wv, bv, Mv);
    final_out<<<dim3(4, 6), blk, 0, stream>>>(Mv, Wo, bo, out);
}